// Round 23
// baseline (160.970 us; speedup 1.0000x reference)
//
#include <hip/hip_runtime.h>

// VectorQuantizer: fused MFMA bf16 filter + bit-exact numpy recheck + gather.
// x [64,64,64,64] f32 -> flat [N=262144, D=64]; emb [D=64, K=512].
// out = concat(quantized_st flat [16777216], loss [1]) as f32.
//
// R23 = R22 (157.9us best) + s_setprio(1) around both sweep j-loops
// (catalog T5). Mechanism: 1024 independent WGs at different phases
// (sweep/recheck/gather) = wave role diversity -> scheduler can favor
// MFMA-chain waves over memory-phase waves (attn-like regime, +4-7%
// measured; NOT the lockstep-GEMM null regime). Everything else is
// byte-identical to R22 (absmax 0.0, R2/R5-R22 family).
//
// Exact numpy semantics on candidates:
//   dist = fl(fl(z2+e2[k]) - 2*dot), dot = sequential fmaf d=0..63,
//   z2 = np pairwise_sum, e2 = sequential d-ascending, argmin strict-<
//   first-occurrence == lexicographic u64 min of (distbits<<32)|k [dist>0].
// bf16 filter: t = fmaf(-2, acc, e2c) in BOTH sweeps; MARGIN=0.09 >>
// 2*max bf16-vs-np t-error (~0.02-0.04) (R6-R22 validated).
//
// ws layout (bytes):
//   0      : float  et[512*64]    131072  (f32 codebook, code-major)
//   131072 : float  e2[512]         2048  (np-order norms, exact)
//   133120 : u16    ebT[512*64]    65536  (bf16 codebook, code-major)
//   198656 : double partials[1024]  8192  (per-block loss partials)

#define NROWS 262144
#define D 64
#define K 512
#define MARGIN 0.09f
#define INF32 3.4e38f

#define WS_ET 0
#define WS_E2 131072
#define WS_EBT 133120
#define WS_PARTIALS 198656

typedef __attribute__((ext_vector_type(8))) short bf16x8;
typedef __attribute__((ext_vector_type(4))) float f32x4;

__device__ inline unsigned short f2bf(float f) {  // RTNE, finite inputs
    unsigned u = __float_as_uint(f);
    u += 0x7fffu + ((u >> 16) & 1u);
    return (unsigned short)(u >> 16);
}
__device__ inline unsigned pack_bf2(float lo, float hi) {
    unsigned ulo = __float_as_uint(lo); ulo += 0x7fffu + ((ulo >> 16) & 1u);
    unsigned uhi = __float_as_uint(hi); uhi += 0x7fffu + ((uhi >> 16) & 1u);
    return (ulo >> 16) | (uhi & 0xffff0000u);
}
__device__ inline bf16x8 pack8(float4 p, float4 q) {
    union { unsigned u[4]; bf16x8 v; } r;
    r.u[0] = pack_bf2(p.x, p.y); r.u[1] = pack_bf2(p.z, p.w);
    r.u[2] = pack_bf2(q.x, q.y); r.u[3] = pack_bf2(q.z, q.w);
    return r.v;
}

// ---- K1: codebook prep (8 blocks x 64 threads, one code per thread) ----
__global__ void __launch_bounds__(64) vq_prep(const float* __restrict__ emb, char* ws) {
    float* e2 = (float*)(ws + WS_E2);
    float* et = (float*)(ws + WS_ET);
    unsigned short* ebT = (unsigned short*)(ws + WS_EBT);
    int k = blockIdx.x * 64 + threadIdx.x;
    float v0 = emb[k];
    et[k * D] = v0;
    ebT[k * D] = f2bf(v0);
    float s = __fmul_rn(v0, v0);
    for (int d = 1; d < D; ++d) {
        float v = emb[d * K + k];
        et[k * D + d] = v;
        ebT[k * D + d] = f2bf(v);
        s = __fadd_rn(s, __fmul_rn(v, v));  // sequential d (np axis-0 reduce)
    }
    e2[k] = s;
}

// ---- exact np-order dist for one (row, k), packed (distbits<<32)|k ----
static __device__ __forceinline__ unsigned long long exact_pack(
        const float* __restrict__ x, const float* __restrict__ et,
        const float* __restrict__ e2f, int row, int k) {
    const float* xr = x + (size_t)row * D;
    float r0 = __fmul_rn(xr[0], xr[0]), r1 = __fmul_rn(xr[1], xr[1]);
    float r2 = __fmul_rn(xr[2], xr[2]), r3 = __fmul_rn(xr[3], xr[3]);
    float r4 = __fmul_rn(xr[4], xr[4]), r5 = __fmul_rn(xr[5], xr[5]);
    float r6 = __fmul_rn(xr[6], xr[6]), r7 = __fmul_rn(xr[7], xr[7]);
    for (int i = 8; i < 64; i += 8) {
        r0 = __fadd_rn(r0, __fmul_rn(xr[i],     xr[i]));
        r1 = __fadd_rn(r1, __fmul_rn(xr[i + 1], xr[i + 1]));
        r2 = __fadd_rn(r2, __fmul_rn(xr[i + 2], xr[i + 2]));
        r3 = __fadd_rn(r3, __fmul_rn(xr[i + 3], xr[i + 3]));
        r4 = __fadd_rn(r4, __fmul_rn(xr[i + 4], xr[i + 4]));
        r5 = __fadd_rn(r5, __fmul_rn(xr[i + 5], xr[i + 5]));
        r6 = __fadd_rn(r6, __fmul_rn(xr[i + 6], xr[i + 6]));
        r7 = __fadd_rn(r7, __fmul_rn(xr[i + 7], xr[i + 7]));
    }
    float z2 = __fadd_rn(__fadd_rn(__fadd_rn(r0, r1), __fadd_rn(r2, r3)),
                         __fadd_rn(__fadd_rn(r4, r5), __fadd_rn(r6, r7)));
    const float* ep = et + (size_t)k * D;
    float a = 0.f;
    for (int d = 0; d < D; ++d) a = fmaf(xr[d], ep[d], a);  // sequential np chain
    float dist = __fsub_rn(__fadd_rn(z2, e2f[k]), __fmul_rn(2.0f, a));
    return ((unsigned long long)__float_as_uint(dist) << 32) | (unsigned)k;
}

// ---- K2: fused filter + recheck + gather. 4 waves x 64 rows = 256 rows ----
__global__ void __launch_bounds__(256)
__attribute__((amdgpu_waves_per_eu(4, 4)))
vq_fused(const float* __restrict__ x, float* __restrict__ out,
         char* __restrict__ ws) {
    const float* et  = (const float*)(ws + WS_ET);
    const float* e2f = (const float*)(ws + WS_E2);
    const unsigned short* ebT = (const unsigned short*)(ws + WS_EBT);
    double* partials = (double*)(ws + WS_PARTIALS);

    __shared__ float le2[512];
    __shared__ unsigned long long lgmin[256];
    __shared__ unsigned cl[4096];
    __shared__ double red[256];
    __shared__ int ccnt;
    __shared__ int ovf;

    const int tid = threadIdx.x;
    const int wv = tid >> 6, lane = tid & 63;
    const int c15 = lane & 15;
    const int g = lane >> 4;
    const int kofs = g * 8;
    const int gr4 = g * 4;
    // XCD-bijective swizzle: 1024 blocks, 128/XCD contiguous (1024%8==0)
    const int bswz = ((int)blockIdx.x & 7) * 128 + ((int)blockIdx.x >> 3);
    const int blockRow0 = bswz * 256;
    const int rowBase = blockRow0 + wv * 64;   // this wave's 64 rows

    lgmin[tid] = 0xFFFFFFFFFFFFFFFFULL;
    if (tid == 0) { ccnt = 0; ovf = 0; }
    le2[tid] = e2f[tid];
    le2[tid + 256] = e2f[tid + 256];

    // hoist A: convert own x rows to bf16 fragments in registers (once)
    bf16x8 aA0, aA1, aB0, aB1, aC0, aC1, aD0, aD1;
#define LOADA(RT, A0, A1) { \
    const float* xp = x + ((size_t)(rowBase + (RT) * 16 + c15)) * D + kofs; \
    float4 p0 = *(const float4*)xp; \
    float4 p1 = *(const float4*)(xp + 4); \
    float4 p2 = *(const float4*)(xp + 32); \
    float4 p3 = *(const float4*)(xp + 36); \
    A0 = pack8(p0, p1); A1 = pack8(p2, p3); }
    LOADA(0, aA0, aA1) LOADA(1, aB0, aB1) LOADA(2, aC0, aC1) LOADA(3, aD0, aD1)
#undef LOADA

    __syncthreads();

    float m00 = INF32, m01 = INF32, m02 = INF32, m03 = INF32;
    float m10 = INF32, m11 = INF32, m12 = INF32, m13 = INF32;
    float m20 = INF32, m21 = INF32, m22 = INF32, m23 = INF32;
    float m30 = INF32, m31 = INF32, m32 = INF32, m33 = INF32;

    // lane's B-fragment column base; stride 1024 shorts per j
    const unsigned short* bbase = ebT + ((size_t)c15 << 6) + kofs;

    // sweep1: row minima of t = fmaf(-2, dot_bf, e2[k]); j unrolled x2,
    // DEPTH-2 prefetch: 4 independent B loads in flight during 16 MFMAs.
    // T5: setprio(1) biases scheduler toward this MFMA-chain phase.
#define SW1(A0, A1, M0, M1, M2, M3) { \
    f32x4 acc = {0.f, 0.f, 0.f, 0.f}; \
    acc = __builtin_amdgcn_mfma_f32_16x16x32_bf16(A0, bb0, acc, 0, 0, 0); \
    acc = __builtin_amdgcn_mfma_f32_16x16x32_bf16(A1, bb1, acc, 0, 0, 0); \
    M0 = fminf(M0, fmaf(-2.0f, acc[0], e2c)); \
    M1 = fminf(M1, fmaf(-2.0f, acc[1], e2c)); \
    M2 = fminf(M2, fmaf(-2.0f, acc[2], e2c)); \
    M3 = fminf(M3, fmaf(-2.0f, acc[3], e2c)); }

    __builtin_amdgcn_s_setprio(1);
    {
        bf16x8 b00 = *(const bf16x8*)bbase;
        bf16x8 b01 = *(const bf16x8*)(bbase + 32);
        bf16x8 b10 = *(const bf16x8*)(bbase + 1024);
        bf16x8 b11 = *(const bf16x8*)(bbase + 1056);
        for (int jb = 0; jb < 32; jb += 2) {
            const unsigned short* p2 = bbase + (((jb + 2) & 31) << 10);
            const unsigned short* p3 = bbase + (((jb + 3) & 31) << 10);
            bf16x8 n20 = *(const bf16x8*)p2;          // 4 loads in flight
            bf16x8 n21 = *(const bf16x8*)(p2 + 32);
            bf16x8 n30 = *(const bf16x8*)p3;
            bf16x8 n31 = *(const bf16x8*)(p3 + 32);
            {
                bf16x8 bb0 = b00, bb1 = b01;
                float e2c = le2[jb * 16 + c15];
                SW1(aA0, aA1, m00, m01, m02, m03)
                SW1(aB0, aB1, m10, m11, m12, m13)
                SW1(aC0, aC1, m20, m21, m22, m23)
                SW1(aD0, aD1, m30, m31, m32, m33)
            }
            {
                bf16x8 bb0 = b10, bb1 = b11;
                float e2c = le2[(jb + 1) * 16 + c15];
                SW1(aA0, aA1, m00, m01, m02, m03)
                SW1(aB0, aB1, m10, m11, m12, m13)
                SW1(aC0, aC1, m20, m21, m22, m23)
                SW1(aD0, aD1, m30, m31, m32, m33)
            }
            b00 = n20; b01 = n21; b10 = n30; b11 = n31;
        }
    }
    __builtin_amdgcn_s_setprio(0);
#undef SW1

    // min across the 16 lanes (cols) of each lane-group, then add margin
#define RED(v) v = fminf(v, __shfl_xor(v, 1)); v = fminf(v, __shfl_xor(v, 2)); \
               v = fminf(v, __shfl_xor(v, 4)); v = fminf(v, __shfl_xor(v, 8)); \
               v += MARGIN;
    RED(m00) RED(m01) RED(m02) RED(m03)
    RED(m10) RED(m11) RED(m12) RED(m13)
    RED(m20) RED(m21) RED(m22) RED(m23)
    RED(m30) RED(m31) RED(m32) RED(m33)
#undef RED

    // sweep2: collect candidates t <= rowmin + MARGIN. NO CALLS in loop.
#define PUSH(RT, R, KK) { int idx = atomicAdd(&ccnt, 1); \
    if (idx < 4096) cl[idx] = \
        ((unsigned)(wv * 64 + (RT) * 16 + gr4 + (R)) << 9) | (unsigned)(KK); \
    else ovf = 1; }

#define SW2(RT, A0, A1, M0, M1, M2, M3, KK) { \
    f32x4 acc = {0.f, 0.f, 0.f, 0.f}; \
    acc = __builtin_amdgcn_mfma_f32_16x16x32_bf16(A0, bb0, acc, 0, 0, 0); \
    acc = __builtin_amdgcn_mfma_f32_16x16x32_bf16(A1, bb1, acc, 0, 0, 0); \
    if (fmaf(-2.0f, acc[0], e2c) <= M0) PUSH(RT, 0, KK) \
    if (fmaf(-2.0f, acc[1], e2c) <= M1) PUSH(RT, 1, KK) \
    if (fmaf(-2.0f, acc[2], e2c) <= M2) PUSH(RT, 2, KK) \
    if (fmaf(-2.0f, acc[3], e2c) <= M3) PUSH(RT, 3, KK) }

    __builtin_amdgcn_s_setprio(1);
    {
        bf16x8 b00 = *(const bf16x8*)bbase;
        bf16x8 b01 = *(const bf16x8*)(bbase + 32);
        bf16x8 b10 = *(const bf16x8*)(bbase + 1024);
        bf16x8 b11 = *(const bf16x8*)(bbase + 1056);
        for (int jb = 0; jb < 32; jb += 2) {
            const unsigned short* p2 = bbase + (((jb + 2) & 31) << 10);
            const unsigned short* p3 = bbase + (((jb + 3) & 31) << 10);
            bf16x8 n20 = *(const bf16x8*)p2;          // 4 loads in flight
            bf16x8 n21 = *(const bf16x8*)(p2 + 32);
            bf16x8 n30 = *(const bf16x8*)p3;
            bf16x8 n31 = *(const bf16x8*)(p3 + 32);
            {
                bf16x8 bb0 = b00, bb1 = b01;
                const int kkl = jb * 16 + c15;
                float e2c = le2[kkl];
                SW2(0, aA0, aA1, m00, m01, m02, m03, kkl)
                SW2(1, aB0, aB1, m10, m11, m12, m13, kkl)
                SW2(2, aC0, aC1, m20, m21, m22, m23, kkl)
                SW2(3, aD0, aD1, m30, m31, m32, m33, kkl)
            }
            {
                bf16x8 bb0 = b10, bb1 = b11;
                const int kkl = (jb + 1) * 16 + c15;
                float e2c = le2[kkl];
                SW2(0, aA0, aA1, m00, m01, m02, m03, kkl)
                SW2(1, aB0, aB1, m10, m11, m12, m13, kkl)
                SW2(2, aC0, aC1, m20, m21, m22, m23, kkl)
                SW2(3, aD0, aD1, m30, m31, m32, m33, kkl)
            }
            b00 = n20; b01 = n21; b10 = n30; b11 = n31;
        }
    }
    __builtin_amdgcn_s_setprio(0);
#undef SW2
#undef PUSH

    __syncthreads();
    // exact recheck of listed candidates (block-private rows -> LDS atomicMin)
    const int cnt = (ccnt < 4096) ? ccnt : 4096;
    for (int i = tid; i < cnt; i += 256) {
        unsigned e = cl[i];
        int rowLocal = (int)(e >> 9);
        int k = (int)(e & 0x1ffu);
        atomicMin(&lgmin[rowLocal], exact_pack(x, et, e2f, blockRow0 + rowLocal, k));
    }
    // overflow fallback: full exact rescan (never taken: ~440 cands << 4096)
    if (ovf) {
        for (int p = tid; p < 256 * 512; p += 256)
            atomicMin(&lgmin[p >> 9],
                      exact_pack(x, et, e2f, blockRow0 + (p >> 9), p & 0x1ff));
    }
    __syncthreads();

    // gather winning code; out = fl(x + fl(q - x)); fp64 loss partial
    const int row = blockRow0 + tid;
    const int kb = (int)(lgmin[tid] & 0xFFFFFFFFULL);
    const float4* cq = (const float4*)(et + (size_t)kb * D);
    const float4* xr = (const float4*)(x + (size_t)row * D);
    float4* outr = (float4*)(out + (size_t)row * D);
    double rs = 0.0;
#define OUTQ(G) { \
        float4 e4 = cq[G]; float4 xv = xr[G]; float4 o; \
        float d0 = __fsub_rn(e4.x, xv.x); \
        float d1 = __fsub_rn(e4.y, xv.y); \
        float d2 = __fsub_rn(e4.z, xv.z); \
        float d3 = __fsub_rn(e4.w, xv.w); \
        o.x = __fadd_rn(xv.x, d0); \
        o.y = __fadd_rn(xv.y, d1); \
        o.z = __fadd_rn(xv.z, d2); \
        o.w = __fadd_rn(xv.w, d3); \
        outr[G] = o; \
        rs += (double)__fmul_rn(d0, d0) + (double)__fmul_rn(d1, d1) + \
              (double)__fmul_rn(d2, d2) + (double)__fmul_rn(d3, d3); }
    OUTQ(0) OUTQ(1) OUTQ(2) OUTQ(3) OUTQ(4) OUTQ(5) OUTQ(6) OUTQ(7)
    OUTQ(8) OUTQ(9) OUTQ(10) OUTQ(11) OUTQ(12) OUTQ(13) OUTQ(14) OUTQ(15)
#undef OUTQ

    red[tid] = rs;
    __syncthreads();
    for (int s = 128; s > 0; s >>= 1) {
        if (tid < s) red[tid] += red[tid + s];
        __syncthreads();
    }
    if (tid == 0) partials[bswz] = red[0];
}

// ---- K3: finalize loss over 1024 partials ----
__global__ void __launch_bounds__(256) vq_finalize(float* __restrict__ out, char* ws) {
    const double* partials = (const double*)(ws + WS_PARTIALS);
    __shared__ double red[256];
    double s = partials[threadIdx.x] + partials[threadIdx.x + 256] +
               partials[threadIdx.x + 512] + partials[threadIdx.x + 768];
    red[threadIdx.x] = s;
    __syncthreads();
    for (int st = 128; st > 0; st >>= 1) {
        if (threadIdx.x < st) red[threadIdx.x] += red[threadIdx.x + st];
        __syncthreads();
    }
    if (threadIdx.x == 0) {
        out[16777216] = (float)(1.25 * red[0] / 16777216.0);
    }
}

extern "C" void kernel_launch(void* const* d_in, const int* in_sizes, int n_in,
                              void* d_out, int out_size, void* d_ws, size_t ws_size,
                              hipStream_t stream) {
    const float* x   = (const float*)d_in[0];
    const float* emb = (const float*)d_in[1];
    float* out = (float*)d_out;
    char* ws = (char*)d_ws;

    vq_prep<<<8, 64, 0, stream>>>(emb, ws);
    vq_fused<<<NROWS / 256, 256, 0, stream>>>(x, out, ws);
    vq_finalize<<<1, 256, 0, stream>>>(out, ws);
}

// Round 24
// 157.634 us; speedup vs baseline: 1.0212x; 1.0212x over previous
//
#include <hip/hip_runtime.h>

// VectorQuantizer: fused MFMA bf16 filter + bit-exact numpy recheck + gather.
// x [64,64,64,64] f32 -> flat [N=262144, D=64]; emb [D=64, K=512].
// out = concat(quantized_st flat [16777216], loss [1]) as f32.
//
// R24 = exact revert to R22 (157.9us, session best). R23's setprio (T5)
// was null-to-negative per the pre-committed falsifier -> scheduler is not
// the residual cost. Final configuration: 4-wave WGs x 1024 blocks,
// 64 rows/wave (R17 body), depth-2 B prefetch from L2-hot ebT,
// two-sweep margin filter + exact numpy recheck + fused gather.
//
// Exact numpy semantics (proven absmax 0.0 R2/R5-R23) on candidates:
//   dist = fl(fl(z2+e2[k]) - 2*dot), dot = sequential fmaf d=0..63,
//   z2 = np pairwise_sum, e2 = sequential d-ascending, argmin strict-<
//   first-occurrence == lexicographic u64 min of (distbits<<32)|k [dist>0].
// bf16 filter: t = fmaf(-2, acc, e2c) in BOTH sweeps; MARGIN=0.09 >>
// 2*max bf16-vs-np t-error (~0.02-0.04) (R6-R23 validated).
//
// ws layout (bytes):
//   0      : float  et[512*64]    131072  (f32 codebook, code-major)
//   131072 : float  e2[512]         2048  (np-order norms, exact)
//   133120 : u16    ebT[512*64]    65536  (bf16 codebook, code-major)
//   198656 : double partials[1024]  8192  (per-block loss partials)

#define NROWS 262144
#define D 64
#define K 512
#define MARGIN 0.09f
#define INF32 3.4e38f

#define WS_ET 0
#define WS_E2 131072
#define WS_EBT 133120
#define WS_PARTIALS 198656

typedef __attribute__((ext_vector_type(8))) short bf16x8;
typedef __attribute__((ext_vector_type(4))) float f32x4;

__device__ inline unsigned short f2bf(float f) {  // RTNE, finite inputs
    unsigned u = __float_as_uint(f);
    u += 0x7fffu + ((u >> 16) & 1u);
    return (unsigned short)(u >> 16);
}
__device__ inline unsigned pack_bf2(float lo, float hi) {
    unsigned ulo = __float_as_uint(lo); ulo += 0x7fffu + ((ulo >> 16) & 1u);
    unsigned uhi = __float_as_uint(hi); uhi += 0x7fffu + ((uhi >> 16) & 1u);
    return (ulo >> 16) | (uhi & 0xffff0000u);
}
__device__ inline bf16x8 pack8(float4 p, float4 q) {
    union { unsigned u[4]; bf16x8 v; } r;
    r.u[0] = pack_bf2(p.x, p.y); r.u[1] = pack_bf2(p.z, p.w);
    r.u[2] = pack_bf2(q.x, q.y); r.u[3] = pack_bf2(q.z, q.w);
    return r.v;
}

// ---- K1: codebook prep (8 blocks x 64 threads, one code per thread) ----
__global__ void __launch_bounds__(64) vq_prep(const float* __restrict__ emb, char* ws) {
    float* e2 = (float*)(ws + WS_E2);
    float* et = (float*)(ws + WS_ET);
    unsigned short* ebT = (unsigned short*)(ws + WS_EBT);
    int k = blockIdx.x * 64 + threadIdx.x;
    float v0 = emb[k];
    et[k * D] = v0;
    ebT[k * D] = f2bf(v0);
    float s = __fmul_rn(v0, v0);
    for (int d = 1; d < D; ++d) {
        float v = emb[d * K + k];
        et[k * D + d] = v;
        ebT[k * D + d] = f2bf(v);
        s = __fadd_rn(s, __fmul_rn(v, v));  // sequential d (np axis-0 reduce)
    }
    e2[k] = s;
}

// ---- exact np-order dist for one (row, k), packed (distbits<<32)|k ----
static __device__ __forceinline__ unsigned long long exact_pack(
        const float* __restrict__ x, const float* __restrict__ et,
        const float* __restrict__ e2f, int row, int k) {
    const float* xr = x + (size_t)row * D;
    float r0 = __fmul_rn(xr[0], xr[0]), r1 = __fmul_rn(xr[1], xr[1]);
    float r2 = __fmul_rn(xr[2], xr[2]), r3 = __fmul_rn(xr[3], xr[3]);
    float r4 = __fmul_rn(xr[4], xr[4]), r5 = __fmul_rn(xr[5], xr[5]);
    float r6 = __fmul_rn(xr[6], xr[6]), r7 = __fmul_rn(xr[7], xr[7]);
    for (int i = 8; i < 64; i += 8) {
        r0 = __fadd_rn(r0, __fmul_rn(xr[i],     xr[i]));
        r1 = __fadd_rn(r1, __fmul_rn(xr[i + 1], xr[i + 1]));
        r2 = __fadd_rn(r2, __fmul_rn(xr[i + 2], xr[i + 2]));
        r3 = __fadd_rn(r3, __fmul_rn(xr[i + 3], xr[i + 3]));
        r4 = __fadd_rn(r4, __fmul_rn(xr[i + 4], xr[i + 4]));
        r5 = __fadd_rn(r5, __fmul_rn(xr[i + 5], xr[i + 5]));
        r6 = __fadd_rn(r6, __fmul_rn(xr[i + 6], xr[i + 6]));
        r7 = __fadd_rn(r7, __fmul_rn(xr[i + 7], xr[i + 7]));
    }
    float z2 = __fadd_rn(__fadd_rn(__fadd_rn(r0, r1), __fadd_rn(r2, r3)),
                         __fadd_rn(__fadd_rn(r4, r5), __fadd_rn(r6, r7)));
    const float* ep = et + (size_t)k * D;
    float a = 0.f;
    for (int d = 0; d < D; ++d) a = fmaf(xr[d], ep[d], a);  // sequential np chain
    float dist = __fsub_rn(__fadd_rn(z2, e2f[k]), __fmul_rn(2.0f, a));
    return ((unsigned long long)__float_as_uint(dist) << 32) | (unsigned)k;
}

// ---- K2: fused filter + recheck + gather. 4 waves x 64 rows = 256 rows ----
__global__ void __launch_bounds__(256)
__attribute__((amdgpu_waves_per_eu(4, 4)))
vq_fused(const float* __restrict__ x, float* __restrict__ out,
         char* __restrict__ ws) {
    const float* et  = (const float*)(ws + WS_ET);
    const float* e2f = (const float*)(ws + WS_E2);
    const unsigned short* ebT = (const unsigned short*)(ws + WS_EBT);
    double* partials = (double*)(ws + WS_PARTIALS);

    __shared__ float le2[512];
    __shared__ unsigned long long lgmin[256];
    __shared__ unsigned cl[4096];
    __shared__ double red[256];
    __shared__ int ccnt;
    __shared__ int ovf;

    const int tid = threadIdx.x;
    const int wv = tid >> 6, lane = tid & 63;
    const int c15 = lane & 15;
    const int g = lane >> 4;
    const int kofs = g * 8;
    const int gr4 = g * 4;
    // XCD-bijective swizzle: 1024 blocks, 128/XCD contiguous (1024%8==0)
    const int bswz = ((int)blockIdx.x & 7) * 128 + ((int)blockIdx.x >> 3);
    const int blockRow0 = bswz * 256;
    const int rowBase = blockRow0 + wv * 64;   // this wave's 64 rows

    lgmin[tid] = 0xFFFFFFFFFFFFFFFFULL;
    if (tid == 0) { ccnt = 0; ovf = 0; }
    le2[tid] = e2f[tid];
    le2[tid + 256] = e2f[tid + 256];

    // hoist A: convert own x rows to bf16 fragments in registers (once)
    bf16x8 aA0, aA1, aB0, aB1, aC0, aC1, aD0, aD1;
#define LOADA(RT, A0, A1) { \
    const float* xp = x + ((size_t)(rowBase + (RT) * 16 + c15)) * D + kofs; \
    float4 p0 = *(const float4*)xp; \
    float4 p1 = *(const float4*)(xp + 4); \
    float4 p2 = *(const float4*)(xp + 32); \
    float4 p3 = *(const float4*)(xp + 36); \
    A0 = pack8(p0, p1); A1 = pack8(p2, p3); }
    LOADA(0, aA0, aA1) LOADA(1, aB0, aB1) LOADA(2, aC0, aC1) LOADA(3, aD0, aD1)
#undef LOADA

    __syncthreads();

    float m00 = INF32, m01 = INF32, m02 = INF32, m03 = INF32;
    float m10 = INF32, m11 = INF32, m12 = INF32, m13 = INF32;
    float m20 = INF32, m21 = INF32, m22 = INF32, m23 = INF32;
    float m30 = INF32, m31 = INF32, m32 = INF32, m33 = INF32;

    // lane's B-fragment column base; stride 1024 shorts per j
    const unsigned short* bbase = ebT + ((size_t)c15 << 6) + kofs;

    // sweep1: row minima of t = fmaf(-2, dot_bf, e2[k]); j unrolled x2,
    // DEPTH-2 prefetch: 4 independent B loads in flight during 16 MFMAs.
#define SW1(A0, A1, M0, M1, M2, M3) { \
    f32x4 acc = {0.f, 0.f, 0.f, 0.f}; \
    acc = __builtin_amdgcn_mfma_f32_16x16x32_bf16(A0, bb0, acc, 0, 0, 0); \
    acc = __builtin_amdgcn_mfma_f32_16x16x32_bf16(A1, bb1, acc, 0, 0, 0); \
    M0 = fminf(M0, fmaf(-2.0f, acc[0], e2c)); \
    M1 = fminf(M1, fmaf(-2.0f, acc[1], e2c)); \
    M2 = fminf(M2, fmaf(-2.0f, acc[2], e2c)); \
    M3 = fminf(M3, fmaf(-2.0f, acc[3], e2c)); }

    {
        bf16x8 b00 = *(const bf16x8*)bbase;
        bf16x8 b01 = *(const bf16x8*)(bbase + 32);
        bf16x8 b10 = *(const bf16x8*)(bbase + 1024);
        bf16x8 b11 = *(const bf16x8*)(bbase + 1056);
        for (int jb = 0; jb < 32; jb += 2) {
            const unsigned short* p2 = bbase + (((jb + 2) & 31) << 10);
            const unsigned short* p3 = bbase + (((jb + 3) & 31) << 10);
            bf16x8 n20 = *(const bf16x8*)p2;          // 4 loads in flight
            bf16x8 n21 = *(const bf16x8*)(p2 + 32);
            bf16x8 n30 = *(const bf16x8*)p3;
            bf16x8 n31 = *(const bf16x8*)(p3 + 32);
            {
                bf16x8 bb0 = b00, bb1 = b01;
                float e2c = le2[jb * 16 + c15];
                SW1(aA0, aA1, m00, m01, m02, m03)
                SW1(aB0, aB1, m10, m11, m12, m13)
                SW1(aC0, aC1, m20, m21, m22, m23)
                SW1(aD0, aD1, m30, m31, m32, m33)
            }
            {
                bf16x8 bb0 = b10, bb1 = b11;
                float e2c = le2[(jb + 1) * 16 + c15];
                SW1(aA0, aA1, m00, m01, m02, m03)
                SW1(aB0, aB1, m10, m11, m12, m13)
                SW1(aC0, aC1, m20, m21, m22, m23)
                SW1(aD0, aD1, m30, m31, m32, m33)
            }
            b00 = n20; b01 = n21; b10 = n30; b11 = n31;
        }
    }
#undef SW1

    // min across the 16 lanes (cols) of each lane-group, then add margin
#define RED(v) v = fminf(v, __shfl_xor(v, 1)); v = fminf(v, __shfl_xor(v, 2)); \
               v = fminf(v, __shfl_xor(v, 4)); v = fminf(v, __shfl_xor(v, 8)); \
               v += MARGIN;
    RED(m00) RED(m01) RED(m02) RED(m03)
    RED(m10) RED(m11) RED(m12) RED(m13)
    RED(m20) RED(m21) RED(m22) RED(m23)
    RED(m30) RED(m31) RED(m32) RED(m33)
#undef RED

    // sweep2: collect candidates t <= rowmin + MARGIN. NO CALLS in loop.
#define PUSH(RT, R, KK) { int idx = atomicAdd(&ccnt, 1); \
    if (idx < 4096) cl[idx] = \
        ((unsigned)(wv * 64 + (RT) * 16 + gr4 + (R)) << 9) | (unsigned)(KK); \
    else ovf = 1; }

#define SW2(RT, A0, A1, M0, M1, M2, M3, KK) { \
    f32x4 acc = {0.f, 0.f, 0.f, 0.f}; \
    acc = __builtin_amdgcn_mfma_f32_16x16x32_bf16(A0, bb0, acc, 0, 0, 0); \
    acc = __builtin_amdgcn_mfma_f32_16x16x32_bf16(A1, bb1, acc, 0, 0, 0); \
    if (fmaf(-2.0f, acc[0], e2c) <= M0) PUSH(RT, 0, KK) \
    if (fmaf(-2.0f, acc[1], e2c) <= M1) PUSH(RT, 1, KK) \
    if (fmaf(-2.0f, acc[2], e2c) <= M2) PUSH(RT, 2, KK) \
    if (fmaf(-2.0f, acc[3], e2c) <= M3) PUSH(RT, 3, KK) }

    {
        bf16x8 b00 = *(const bf16x8*)bbase;
        bf16x8 b01 = *(const bf16x8*)(bbase + 32);
        bf16x8 b10 = *(const bf16x8*)(bbase + 1024);
        bf16x8 b11 = *(const bf16x8*)(bbase + 1056);
        for (int jb = 0; jb < 32; jb += 2) {
            const unsigned short* p2 = bbase + (((jb + 2) & 31) << 10);
            const unsigned short* p3 = bbase + (((jb + 3) & 31) << 10);
            bf16x8 n20 = *(const bf16x8*)p2;          // 4 loads in flight
            bf16x8 n21 = *(const bf16x8*)(p2 + 32);
            bf16x8 n30 = *(const bf16x8*)p3;
            bf16x8 n31 = *(const bf16x8*)(p3 + 32);
            {
                bf16x8 bb0 = b00, bb1 = b01;
                const int kkl = jb * 16 + c15;
                float e2c = le2[kkl];
                SW2(0, aA0, aA1, m00, m01, m02, m03, kkl)
                SW2(1, aB0, aB1, m10, m11, m12, m13, kkl)
                SW2(2, aC0, aC1, m20, m21, m22, m23, kkl)
                SW2(3, aD0, aD1, m30, m31, m32, m33, kkl)
            }
            {
                bf16x8 bb0 = b10, bb1 = b11;
                const int kkl = (jb + 1) * 16 + c15;
                float e2c = le2[kkl];
                SW2(0, aA0, aA1, m00, m01, m02, m03, kkl)
                SW2(1, aB0, aB1, m10, m11, m12, m13, kkl)
                SW2(2, aC0, aC1, m20, m21, m22, m23, kkl)
                SW2(3, aD0, aD1, m30, m31, m32, m33, kkl)
            }
            b00 = n20; b01 = n21; b10 = n30; b11 = n31;
        }
    }
#undef SW2
#undef PUSH

    __syncthreads();
    // exact recheck of listed candidates (block-private rows -> LDS atomicMin)
    const int cnt = (ccnt < 4096) ? ccnt : 4096;
    for (int i = tid; i < cnt; i += 256) {
        unsigned e = cl[i];
        int rowLocal = (int)(e >> 9);
        int k = (int)(e & 0x1ffu);
        atomicMin(&lgmin[rowLocal], exact_pack(x, et, e2f, blockRow0 + rowLocal, k));
    }
    // overflow fallback: full exact rescan (never taken: ~440 cands << 4096)
    if (ovf) {
        for (int p = tid; p < 256 * 512; p += 256)
            atomicMin(&lgmin[p >> 9],
                      exact_pack(x, et, e2f, blockRow0 + (p >> 9), p & 0x1ff));
    }
    __syncthreads();

    // gather winning code; out = fl(x + fl(q - x)); fp64 loss partial
    const int row = blockRow0 + tid;
    const int kb = (int)(lgmin[tid] & 0xFFFFFFFFULL);
    const float4* cq = (const float4*)(et + (size_t)kb * D);
    const float4* xr = (const float4*)(x + (size_t)row * D);
    float4* outr = (float4*)(out + (size_t)row * D);
    double rs = 0.0;
#define OUTQ(G) { \
        float4 e4 = cq[G]; float4 xv = xr[G]; float4 o; \
        float d0 = __fsub_rn(e4.x, xv.x); \
        float d1 = __fsub_rn(e4.y, xv.y); \
        float d2 = __fsub_rn(e4.z, xv.z); \
        float d3 = __fsub_rn(e4.w, xv.w); \
        o.x = __fadd_rn(xv.x, d0); \
        o.y = __fadd_rn(xv.y, d1); \
        o.z = __fadd_rn(xv.z, d2); \
        o.w = __fadd_rn(xv.w, d3); \
        outr[G] = o; \
        rs += (double)__fmul_rn(d0, d0) + (double)__fmul_rn(d1, d1) + \
              (double)__fmul_rn(d2, d2) + (double)__fmul_rn(d3, d3); }
    OUTQ(0) OUTQ(1) OUTQ(2) OUTQ(3) OUTQ(4) OUTQ(5) OUTQ(6) OUTQ(7)
    OUTQ(8) OUTQ(9) OUTQ(10) OUTQ(11) OUTQ(12) OUTQ(13) OUTQ(14) OUTQ(15)
#undef OUTQ

    red[tid] = rs;
    __syncthreads();
    for (int s = 128; s > 0; s >>= 1) {
        if (tid < s) red[tid] += red[tid + s];
        __syncthreads();
    }
    if (tid == 0) partials[bswz] = red[0];
}

// ---- K3: finalize loss over 1024 partials ----
__global__ void __launch_bounds__(256) vq_finalize(float* __restrict__ out, char* ws) {
    const double* partials = (const double*)(ws + WS_PARTIALS);
    __shared__ double red[256];
    double s = partials[threadIdx.x] + partials[threadIdx.x + 256] +
               partials[threadIdx.x + 512] + partials[threadIdx.x + 768];
    red[threadIdx.x] = s;
    __syncthreads();
    for (int st = 128; st > 0; st >>= 1) {
        if (threadIdx.x < st) red[threadIdx.x] += red[threadIdx.x + st];
        __syncthreads();
    }
    if (threadIdx.x == 0) {
        out[16777216] = (float)(1.25 * red[0] / 16777216.0);
    }
}

extern "C" void kernel_launch(void* const* d_in, const int* in_sizes, int n_in,
                              void* d_out, int out_size, void* d_ws, size_t ws_size,
                              hipStream_t stream) {
    const float* x   = (const float*)d_in[0];
    const float* emb = (const float*)d_in[1];
    float* out = (float*)d_out;
    char* ws = (char*)d_ws;

    vq_prep<<<8, 64, 0, stream>>>(emb, ws);
    vq_fused<<<NROWS / 256, 256, 0, stream>>>(x, out, ws);
    vq_finalize<<<1, 256, 0, stream>>>(out, ws);
}